// Round 10
// baseline (2296.408 us; speedup 1.0000x reference)
//
#include <hip/hip_runtime.h>
#include <hip/hip_fp16.h>
#include <math.h>

#define NN    6000
#define NPAD  6144
#define NIB   1200
#define NMAXI 80
#define NAVGI 30
#define NBLK  250
#define NTHR  512   // 8 waves/block, 3 rows per wave -> 24 rows/block, 250 blocks

// float(np.sqrt(np.pi))
#define SQRT_PI_F 1.7724538509055160273f

typedef _Float16 half2_t __attribute__((ext_vector_type(2)));

// Inline erfcx, no libcalls. NR erfcc: erfc(x) ~= t*exp(-x^2+P(t)), t=1/(1+x/2)
// => erfcx(x) = t*exp(P(t)) (exp(x^2) cancels analytically; rel err < 1.2e-7)
__device__ __forceinline__ float erfcx_inl(float y) {
  y = fminf(fmaxf(y, -9.0f), 25.0f);
  const float a   = fabsf(y);
  const float a_s = fminf(a, 5.0f);
  const float t   = 1.0f / (1.0f + 0.5f * a_s);
  const float p   = -1.26551223f + t * (1.00002368f + t * (0.37409196f +
                    t * (0.09678418f + t * (-0.18628806f + t * (0.27886807f +
                    t * (-1.13520398f + t * (1.48851587f + t * (-0.82215223f +
                    t * 0.17087277f))))))));
  const float fsm = t * __expf(p);
  const float a_l = fmaxf(a, 5.0f);
  const float flg = (1.0f / (SQRT_PI_F * a_l)) * (1.0f - 0.5f / (a_l * a_l));
  const float f   = (a <= 5.0f) ? fsm : flg;
  return (y >= 0.0f) ? f : 2.0f * __expf(y * y) - f;
}

__device__ __forceinline__ float dot2acc(unsigned w, unsigned r, float acc) {
#if defined(__has_builtin) && __has_builtin(__builtin_amdgcn_fdot2)
  return __builtin_amdgcn_fdot2(__builtin_bit_cast(half2_t, w),
                                __builtin_bit_cast(half2_t, r), acc, false);
#else
  half2_t wh = __builtin_bit_cast(half2_t, w);
  half2_t rh = __builtin_bit_cast(half2_t, r);
  return acc + (float)wh.x * (float)rh.x + (float)wh.y * (float)rh.y;
#endif
}

__device__ __forceinline__ unsigned pksq(unsigned w) {
  half2_t wh = __builtin_bit_cast(half2_t, w);
  half2_t s  = wh * wh;                 // v_pk_mul_f16
  return __builtin_bit_cast(unsigned, s);
}

// Inline sense-reversing global barrier (proven rounds 6-9, deterministic).
__device__ __forceinline__ void gbar(unsigned* cnt, unsigned* gen, int tid) {
  __syncthreads();
  if (tid == 0) {
    __builtin_amdgcn_fence(__ATOMIC_RELEASE, "agent");
    const unsigned g = __hip_atomic_load(gen, __ATOMIC_RELAXED,
                                         __HIP_MEMORY_SCOPE_AGENT);
    const unsigned old = __hip_atomic_fetch_add(cnt, 1u, __ATOMIC_RELAXED,
                                                __HIP_MEMORY_SCOPE_AGENT);
    if (old == NBLK - 1) {
      __hip_atomic_store(cnt, 0u, __ATOMIC_RELAXED, __HIP_MEMORY_SCOPE_AGENT);
      __hip_atomic_store(gen, g + 1u, __ATOMIC_RELEASE,
                         __HIP_MEMORY_SCOPE_AGENT);
    } else {
      while (__hip_atomic_load(gen, __ATOMIC_RELAXED,
                               __HIP_MEMORY_SCOPE_AGENT) == g)
        __builtin_amdgcn_s_sleep(2);
    }
    __builtin_amdgcn_fence(__ATOMIC_ACQUIRE, "agent");
  }
  __syncthreads();
}

__global__ __launch_bounds__(256) void init_kernel(
    const float* __restrict__ contrast, const float* __restrict__ grat,
    const float* __restrict__ pref, float* __restrict__ g0,
    float* __restrict__ g1, float* __restrict__ meanv,
    float* __restrict__ ctab, float* __restrict__ qn, float* __restrict__ qw,
    unsigned* __restrict__ conv, unsigned* __restrict__ bar)
{
  int t = blockIdx.x * 256 + threadIdx.x;
  if (t < NPAD) { g0[t] = 0.0f; g1[t] = 0.0f; }   // r0 = 0, pads = 0
  if (t < NN) {
    double th = (3.141592653589793 - 0.01) * (double)t / 5999.0;
    ctab[t] = cosf(2.0f * (float)th) - 1.0f;
    float d  = grat[0] - pref[t];
    float cg = (cosf(d * 3.14159265358979323846f / 90.0f) - 1.0f) / 1.0966227112321508f;
    meanv[t] = contrast[0] * 20.0f * expf(cg);
  }
  if (t < NMAXI) conv[t] = 0u;
  if (t < 2)     bar[t]  = 0u;     // barrier cnt / gen (re-zeroed every call)
  // 64-pt Gauss-Legendre nodes/weights via Newton on Legendre recurrence (fp64)
  if (blockIdx.x == 0 && threadIdx.x < 64) {
    int m = threadIdx.x;
    double x = cos(3.141592653589793 * (m + 0.75) / 64.5);
    double p0, p1, dp = 1.0;
    for (int it = 0; it < 60; ++it) {
      p0 = 1.0; p1 = x;
      for (int k = 2; k <= 64; ++k) {
        double p2 = ((2.0 * k - 1.0) * x * p1 - (k - 1.0) * p0) / (double)k;
        p0 = p1; p1 = p2;
      }
      dp = 64.0 * (x * p1 - p0) / (x * x - 1.0);
      double step = p1 / dp;
      x -= step;
      if (fabs(step) < 1e-15) break;
    }
    p0 = 1.0; p1 = x;
    for (int k = 2; k <= 64; ++k) {
      double p2 = ((2.0 * k - 1.0) * x * p1 - (k - 1.0) * p0) / (double)k;
      p0 = p1; p1 = p2;
    }
    dp = 64.0 * (x * p1 - p0) / (x * x - 1.0);
    double wgt = 2.0 / ((1.0 - x * x) * dp * dp);
    qn[63 - m] = (float)x;
    qw[63 - m] = (float)wgt;
  }
}

// Persistent kernel, W streamed from workspace.
// Layout: W fp16, rows padded to 6144 (pad = 0). Block b owns rows
// [24b, 24b+24); each wave owns 3 rows. genW is block-local (no global
// barrier needed); the 80-step loop streams W with uint4 (8 fp16) loads --
// 72 MB/iter across the device, L3-resident after iteration 1.
__global__ __launch_bounds__(NTHR) void solve_kernel(
    const float* __restrict__ hyper, const float* __restrict__ randu,
    const float* __restrict__ ctab, const float* __restrict__ meanv,
    const float* __restrict__ qn, const float* __restrict__ qw,
    float* __restrict__ g0, float* __restrict__ g1,
    unsigned short* __restrict__ Wp,
    float* __restrict__ blkmax, unsigned* __restrict__ bar,
    float* __restrict__ out)
{
  const int tid  = threadIdx.x;
  const int lane = tid & 63;
  const int wv   = tid >> 6;
  const int rowA = blockIdx.x * 24 + wv * 3;

  __shared__ float ctabs[NN];
  __shared__ uint4 rh4[NPAD / 8];     // fp16 r: rh4[i] = r[8i..8i+7]
  __shared__ float wmax[8];
  __shared__ float sflag[NAVGI];

  // stage ctab into LDS (used by genW only)
  {
    const float4* c4 = reinterpret_cast<const float4*>(ctab);
    float4* l4 = reinterpret_cast<float4*>(ctabs);
    for (int i = tid; i < NN / 4; i += NTHR) l4[i] = c4[i];
  }
  __syncthreads();

  const float qnl = qn[lane];
  const float qwl = qw[lane];
  const float meanA = meanv[rowA];
  const float meanB = meanv[rowA + 1];
  const float meanC = meanv[rowA + 2];

  // ---- generate this wave's 3 rows of W -> workspace (fp16, padded) ----
  {
    const float cdg = 0.017453292519943295f;   // fp32(pi/180)
    for (int rr = 0; rr < 3; ++rr) {
      const int row = rowA + rr;
      const int ri  = (row < NIB) ? 1 : 0;
      const float eI = hyper[2 + ri], eE = hyper[0 + ri];   // j<NIB : else
      const float pI = hyper[6 + ri], pE = hyper[4 + ri];
      const float wI = cdg * hyper[10 + ri], wE = cdg * hyper[8 + ri];
      const float dI = 4.0f * (wI * wI), dE = 4.0f * (wE * wE);
      const float* ur = randu + (size_t)row * NN;
      unsigned short* wrow = Wp + (size_t)row * NPAD;
#pragma unroll
      for (int k = 0; k < 12; ++k) {
        const int j0 = k * 512 + lane * 8;
        float w[8];
        if (j0 < NN) {   // exact: j0<NN implies all 8 elements valid
          const float4 u0 = *reinterpret_cast<const float4*>(ur + j0);
          const float4 u1 = *reinterpret_cast<const float4*>(ur + j0 + 4);
          const float us[8] = {u0.x, u0.y, u0.z, u0.w, u1.x, u1.y, u1.z, u1.w};
#pragma unroll
          for (int q = 0; q < 8; ++q) {
            const int j = j0 + q;
            int idx = j - row; idx += (idx < 0) ? NN : 0;
            const float ct   = ctabs[idx];
            const float eff  = (j   < NIB) ? eI : eE;
            const float prob = (j   < NIB) ? pI : pE;
            const float den  = (idx < NIB) ? dI : dE;
            const float Z  = __expf(ct / den);
            const float tt = 32.0f * (prob * Z - us[q]);
            w[q] = eff / (1.0f + __expf(-tt));
          }
        } else {
#pragma unroll
          for (int q = 0; q < 8; ++q) w[q] = 0.0f;
        }
        uint4 pk;
        half2_t h;
        h.x = (_Float16)w[0]; h.y = (_Float16)w[1];
        pk.x = __builtin_bit_cast(unsigned, h);
        h.x = (_Float16)w[2]; h.y = (_Float16)w[3];
        pk.y = __builtin_bit_cast(unsigned, h);
        h.x = (_Float16)w[4]; h.y = (_Float16)w[5];
        pk.z = __builtin_bit_cast(unsigned, h);
        h.x = (_Float16)w[6]; h.y = (_Float16)w[7];
        pk.w = __builtin_bit_cast(unsigned, h);
        *reinterpret_cast<uint4*>(wrow + j0) = pk;
      }
    }
  }
  __syncthreads();   // drain stores before first-iteration reads

  const unsigned short* wrA = Wp + (size_t)rowA * NPAD;
  const unsigned short* wrB = Wp + (size_t)(rowA + 1) * NPAD;
  const unsigned short* wrC = Wp + (size_t)(rowA + 2) * NPAD;

  // ---- fixed-point iteration ----
#pragma unroll 1
  for (int t = 0; t < NMAXI; ++t) {
    const float* rcur = (t & 1) ? g1 : g0;
    float*       rnxt = (t & 1) ? g0 : g1;

    // stage r (fp32 global -> fp16 LDS, 8 per uint4 entry)
    {
      const float4* rc4 = reinterpret_cast<const float4*>(rcur);
      for (int i = tid; i < NPAD / 8; i += NTHR) {
        const float4 lo = rc4[i * 2];
        const float4 hi = rc4[i * 2 + 1];
        uint4 pk;
        half2_t h;
        h.x = (_Float16)lo.x; h.y = (_Float16)lo.y;
        pk.x = __builtin_bit_cast(unsigned, h);
        h.x = (_Float16)lo.z; h.y = (_Float16)lo.w;
        pk.y = __builtin_bit_cast(unsigned, h);
        h.x = (_Float16)hi.x; h.y = (_Float16)hi.y;
        pk.z = __builtin_bit_cast(unsigned, h);
        h.x = (_Float16)hi.z; h.y = (_Float16)hi.w;
        pk.w = __builtin_bit_cast(unsigned, h);
        rh4[i] = pk;
      }
    }
    __syncthreads();

    // fused W.r and (W*W).r for three rows; W streamed, uint4 per chunk
    float muA = 0.0f, varA = 0.0f, muB = 0.0f, varB = 0.0f;
    float muC = 0.0f, varC = 0.0f;
#pragma unroll
    for (int k = 0; k < 12; ++k) {
      const int off = k * 512 + lane * 8;
      const uint4 a = *reinterpret_cast<const uint4*>(wrA + off);
      const uint4 b = *reinterpret_cast<const uint4*>(wrB + off);
      const uint4 c = *reinterpret_cast<const uint4*>(wrC + off);
      const uint4 rr = rh4[k * 64 + lane];
      muA  = dot2acc(a.x, rr.x, muA);  muA  = dot2acc(a.y, rr.y, muA);
      muA  = dot2acc(a.z, rr.z, muA);  muA  = dot2acc(a.w, rr.w, muA);
      varA = dot2acc(pksq(a.x), rr.x, varA); varA = dot2acc(pksq(a.y), rr.y, varA);
      varA = dot2acc(pksq(a.z), rr.z, varA); varA = dot2acc(pksq(a.w), rr.w, varA);
      muB  = dot2acc(b.x, rr.x, muB);  muB  = dot2acc(b.y, rr.y, muB);
      muB  = dot2acc(b.z, rr.z, muB);  muB  = dot2acc(b.w, rr.w, muB);
      varB = dot2acc(pksq(b.x), rr.x, varB); varB = dot2acc(pksq(b.y), rr.y, varB);
      varB = dot2acc(pksq(b.z), rr.z, varB); varB = dot2acc(pksq(b.w), rr.w, varB);
      muC  = dot2acc(c.x, rr.x, muC);  muC  = dot2acc(c.y, rr.y, muC);
      muC  = dot2acc(c.z, rr.z, muC);  muC  = dot2acc(c.w, rr.w, muC);
      varC = dot2acc(pksq(c.x), rr.x, varC); varC = dot2acc(pksq(c.y), rr.y, varC);
      varC = dot2acc(pksq(c.z), rr.z, varC); varC = dot2acc(pksq(c.w), rr.w, varC);
    }
#pragma unroll
    for (int off = 32; off > 0; off >>= 1) {
      muA  += __shfl_xor(muA, off);
      varA += __shfl_xor(varA, off);
      muB  += __shfl_xor(muB, off);
      varB += __shfl_xor(varB, off);
      muC  += __shfl_xor(muC, off);
      varC += __shfl_xor(varC, off);
    }

    float ratioM = 0.0f;
#pragma unroll
    for (int rr = 0; rr < 3; ++rr) {
      const int   row = rowA + rr;
      float mu  = ((rr == 0) ? muA  : (rr == 1) ? muB  : muC)
                + ((rr == 0) ? meanA : (rr == 1) ? meanB : meanC);
      float var = ((rr == 0) ? varA : (rr == 1) ? varB : varC) + 25.0f;
      const float sig = sqrtf(var);
      const float uu = (20.0f - mu) / sig;
      const float ll = (10.0f - mu) / sig;
      const float cc = 0.5f * (uu + ll);
      const float hh = 0.5f * (uu - ll);
      const float x = cc + hh * qnl;
      float term    = qwl * erfcx_inl(-x);
#pragma unroll
      for (int off = 32; off > 0; off >>= 1) term += __shfl_xor(term, off);
      const float integ = hh * term;
      const float phiv  = 1.0f / (1.0f + SQRT_PI_F * fmaxf(integ, 0.0f));

      const float rold = rcur[row];           // exact fp32 state
      const float dx   = (phiv - rold) * 0.1f;
      const float rnew = rold + dx;
      ratioM = fmaxf(ratioM, fabsf(dx) / fmaxf(1.0f, fabsf(rnew)));
      if (lane == 0) {
        if (t == NMAXI - 1) out[row] = rnew;
        else                rnxt[row] = rnew;
      }
    }
    if (lane == 0) wmax[wv] = ratioM;
    __syncthreads();
    if (tid == 0) {
      float m = wmax[0];
#pragma unroll
      for (int q = 1; q < 8; ++q) m = fmaxf(m, wmax[q]);
      blkmax[(size_t)t * NBLK + blockIdx.x] = m;
    }
    gbar(bar, bar + 1, tid);
  }

  // ---- convergence epilogue: block 0 reduces blkmax over [50,80) ----
  if (blockIdx.x == 0) {
#pragma unroll
    for (int s = 0; s < 4; ++s) {
      const int t = 50 + wv + 8 * s;
      if (t < NMAXI) {
        float m = 0.0f;   // ratios are >= 0
        for (int p = lane; p < NBLK; p += 64)
          m = fmaxf(m, blkmax[(size_t)t * NBLK + p]);
#pragma unroll
        for (int off = 32; off > 0; off >>= 1)
          m = fmaxf(m, __shfl_xor(m, off));
        if (lane == 0) sflag[t - 50] = (m < 1e-5f) ? 1.0f : 0.0f;
      }
    }
    __syncthreads();
    if (tid == 0) {
      float s = 0.0f;
#pragma unroll
      for (int q = 0; q < NAVGI; ++q) s += sflag[q];
      out[NN] = s / 30.0f;
    }
  }
}

// ---------------- fallback path (round-2 structure, fp32 W in ws) ----------
__global__ __launch_bounds__(256) void genw_kernel(
    const float* __restrict__ hyper, const float* __restrict__ randu,
    const float* __restrict__ ctab, float* __restrict__ Wf)
{
  const int i  = blockIdx.x;
  const int ri = (i < NIB) ? 1 : 0;
  const float eA = hyper[0 + ri], eB = hyper[2 + ri];
  const float pA = hyper[4 + ri], pB = hyper[6 + ri];
  const float c  = 0.017453292519943295f;
  const float wA = c * hyper[8 + ri], wB = c * hyper[10 + ri];
  const float dA = 4.0f * (wA * wA), dB = 4.0f * (wB * wB);
  const float* urow = randu + (size_t)i * NN;
  for (int j4 = threadIdx.x * 4; j4 < NN; j4 += 1024) {
    float4 uv = *reinterpret_cast<const float4*>(urow + j4);
    float us[4] = {uv.x, uv.y, uv.z, uv.w};
    float res[4];
#pragma unroll
    for (int q = 0; q < 4; ++q) {
      int j   = j4 + q;
      int idx = j - i; idx += (idx < 0) ? NN : 0;
      float ct   = ctab[idx];
      float eff  = (j   < NIB) ? eB : eA;
      float prob = (j   < NIB) ? pB : pA;
      float den  = (idx < NIB) ? dB : dA;
      float Z  = __expf(ct / den);
      float tt = 32.0f * (prob * Z - us[q]);
      res[q] = eff / (1.0f + __expf(-tt));
    }
    *reinterpret_cast<float4*>(Wf + (size_t)i * NN + j4) =
        make_float4(res[0], res[1], res[2], res[3]);
  }
}

__global__ __launch_bounds__(256) void iter_kernel(
    const float* __restrict__ Wf, const float* __restrict__ rin,
    float* __restrict__ rout, const float* __restrict__ meanv,
    const float* __restrict__ qn, const float* __restrict__ qw,
    unsigned* __restrict__ convslot)
{
  const int row  = blockIdx.x;
  const int tid  = threadIdx.x;
  const int lane = tid & 63;
  const int wvid = tid >> 6;
  __shared__ float smu[4], svar[4];
  float mu = 0.0f, var = 0.0f;
  const float* wrow = Wf + (size_t)row * NN;
  float4 w[6], r4[6]; bool have[6];
#pragma unroll
  for (int k = 0; k < 6; ++k) {
    const int j = (tid << 2) + (k << 10);
    have[k] = (j < NN);
    if (have[k]) {
      w[k]  = *reinterpret_cast<const float4*>(wrow + j);
      r4[k] = *reinterpret_cast<const float4*>(rin + j);
    }
  }
#pragma unroll
  for (int k = 0; k < 6; ++k) if (have[k]) {
    mu  += w[k].x * r4[k].x + w[k].y * r4[k].y + w[k].z * r4[k].z + w[k].w * r4[k].w;
    var += w[k].x * w[k].x * r4[k].x + w[k].y * w[k].y * r4[k].y
         + w[k].z * w[k].z * r4[k].z + w[k].w * w[k].w * r4[k].w;
  }
#pragma unroll
  for (int off = 32; off > 0; off >>= 1) {
    mu  += __shfl_xor(mu, off);
    var += __shfl_xor(var, off);
  }
  if (lane == 0) { smu[wvid] = mu; svar[wvid] = var; }
  __syncthreads();
  if (tid < 64) {
    mu  = smu[0] + smu[1] + smu[2] + smu[3];
    var = svar[0] + svar[1] + svar[2] + svar[3];
    mu += meanv[row]; var += 25.0f;
    const float sig = sqrtf(var);
    const float uu = (20.0f - mu) / sig;
    const float ll = (10.0f - mu) / sig;
    const float cc = 0.5f * (uu + ll);
    const float hh = 0.5f * (uu - ll);
    const float x = cc + hh * qn[lane];
    float term    = qw[lane] * erfcx_inl(-x);
#pragma unroll
    for (int off = 32; off > 0; off >>= 1) term += __shfl_xor(term, off);
    const float integ = hh * term;
    const float phiv  = 1.0f / (1.0f + SQRT_PI_F * fmaxf(integ, 0.0f));
    const float rold = rin[row];
    const float dx   = (phiv - rold) * 0.1f;
    const float rnew = rold + dx;
    if (lane == 0) {
      rout[row] = rnew;
      const float ratio = fabsf(dx) / fmaxf(1.0f, fabsf(rnew));
      atomicMax(convslot, __float_as_uint(ratio));
    }
  }
}

__global__ __launch_bounds__(256) void final_kernel(
    const float* __restrict__ rfin, const unsigned* __restrict__ conv,
    float* __restrict__ out)
{
  int t = blockIdx.x * 256 + threadIdx.x;
  if (t < NN) out[t] = rfin[t];
  if (t == 6000) {
    float s = 0.0f;
    for (int k = NMAXI - NAVGI; k < NMAXI; ++k)
      s += (__uint_as_float(conv[k]) < 1e-5f) ? 1.0f : 0.0f;
    out[NN] = s / 30.0f;
  }
}

extern "C" void kernel_launch(void* const* d_in, const int* in_sizes, int n_in,
                              void* d_out, int out_size, void* d_ws, size_t ws_size,
                              hipStream_t stream) {
  const float* hyper    = (const float*)d_in[0];
  const float* contrast = (const float*)d_in[1];
  const float* grat     = (const float*)d_in[2];
  const float* pref     = (const float*)d_in[3];
  const float* randu    = (const float*)d_in[4];
  float* out = (float*)d_out;

  char* ws = (char*)d_ws;
  float*    g0     = (float*)(ws + 0);       // 6144 f (r buf A + pad)
  float*    g1     = (float*)(ws + 24576);   // 6144 f (r buf B + pad)
  float*    mn     = (float*)(ws + 49152);   // 6000 f
  float*    ctab   = (float*)(ws + 73152);   // 6000 f
  float*    qn     = (float*)(ws + 97152);   // 64 f
  float*    qw     = (float*)(ws + 97408);   // 64 f
  unsigned* conv   = (unsigned*)(ws + 97664);// 80 u32 (fallback)
  unsigned* bar    = (unsigned*)(ws + 97984);// 2 u32 (barrier cnt/gen)
  float*    blkmax = (float*)(ws + 98304);   // 80*250 f
  unsigned short* Wp = (unsigned short*)(ws + 262144); // fp16 W [6000][6144]
  float*    Wf     = (float*)(ws + 262144);  // fallback fp32 W (exclusive)

  init_kernel<<<24, 256, 0, stream>>>(contrast, grat, pref, g0, g1, mn, ctab,
                                      qn, qw, conv, bar);

  // persistent kernel (cooperative launch for co-residency guarantee)
  {
    const float* a_hyper = hyper;  const float* a_randu = randu;
    const float* a_ctab  = ctab;   const float* a_mn    = mn;
    const float* a_qn    = qn;     const float* a_qw    = qw;
    float* a_g0 = g0; float* a_g1 = g1;
    unsigned short* a_wp = Wp;
    float* a_bm = blkmax; unsigned* a_bar = bar; float* a_out = out;
    void* args[12] = {&a_hyper, &a_randu, &a_ctab, &a_mn, &a_qn, &a_qw,
                      &a_g0, &a_g1, &a_wp, &a_bm, &a_bar, &a_out};
    hipError_t err = hipLaunchCooperativeKernel(
        (const void*)solve_kernel, dim3(NBLK), dim3(NTHR), args, 0, stream);
    if (err == hipSuccess) return;
  }

  // fallback: round-2 structure
  genw_kernel<<<NN, 256, 0, stream>>>(hyper, randu, ctab, Wf);
  float* rb[2] = {g0, g1};
  for (int t = 0; t < NMAXI; ++t) {
    const float* rin = rb[t & 1];
    float*       rou = rb[(t + 1) & 1];
    iter_kernel<<<NN, 256, 0, stream>>>(Wf, rin, rou, mn, qn, qw, conv + t);
  }
  final_kernel<<<24, 256, 0, stream>>>(rb[0], conv, out);
}